// Round 10
// baseline (105.612 us; speedup 1.0000x reference)
//
#include <hip/hip_runtime.h>

#define NB 16384
#define TT 10
#define DIN 256
#define HH 16
#define NG 64      // 4*H
#define NF 160     // T*H

typedef __attribute__((ext_vector_type(8))) _Float16 half8;
typedef __attribute__((ext_vector_type(4))) _Float16 half4;
typedef __attribute__((ext_vector_type(4))) float f32x4;
typedef unsigned int u32;

__device__ __forceinline__ float rl_(float v, int l) {
    return __int_as_float(__builtin_amdgcn_readlane(__float_as_int(v), l));
}

// fire-and-forget 16B/lane global->LDS (lds dest: wave-uniform base + lane*16)
__device__ __forceinline__ void gld16(const float* g, float* l) {
    __builtin_amdgcn_global_load_lds(
        (const __attribute__((address_space(1))) u32*)g,
        (__attribute__((address_space(3))) u32*)l, 16, 0, 0);
}

// K0: one-time prep. B fragments (fp16, lane order) + fused layer-0 bias.
// lane l holds B[col=c*16+(l&15)][k=s*32+(l>>4)*8+j], at Bf[(c*8+s)*64+l].
__global__ __launch_bounds__(256) void k_prep(
        const float* __restrict__ w, const float* __restrict__ bi,
        const float* __restrict__ bh, half8* __restrict__ Bf,
        float* __restrict__ bsum) {
    const int fi = blockIdx.x * 256 + threadIdx.x;   // 0..2047
    const int c = fi >> 9;
    const int s = (fi >> 6) & 7;
    const int ll = fi & 63;
    const int row = c * 16 + (ll & 15);
    const int k0 = s * 32 + ((ll >> 4) << 3);
    const float* wp = w + (size_t)row * DIN + k0;
    float4 a = *(const float4*)wp;
    float4 b = *(const float4*)(wp + 4);
    half8 h;
    h[0] = (_Float16)a.x; h[1] = (_Float16)a.y;
    h[2] = (_Float16)a.z; h[3] = (_Float16)a.w;
    h[4] = (_Float16)b.x; h[5] = (_Float16)b.y;
    h[6] = (_Float16)b.z; h[7] = (_Float16)b.w;
    Bf[fi] = h;
    if (blockIdx.x == 0 && threadIdx.x < NG)
        bsum[threadIdx.x] = bi[threadIdx.x] + bh[threadIdx.x];
}

// K1: xg = x.w^T + bias via f16 MFMA (hi/lo split).
// Row-coalesced persistent version: 512 blocks, each wave owns 5 tiles of
// 16 rows. Per tile: 16 global_load_lds, each reading ONE FULL 1KB row
// (64 lanes x 16B contiguous — perfect coalescing), source pre-swizzled
// (l*16)^((r&7)<<4) so the swizzled ds_read lands right (m201 pattern).
// B fragments live entirely in VGPRs (32 x half8, static indices).
// No barriers at all; per-wave fences only.
__global__ __launch_bounds__(256, 2) void k_proj(
        const float* __restrict__ x, const half8* __restrict__ Bf,
        const float* __restrict__ bsum, _Float16* __restrict__ xgH) {
    __shared__ float xs[4][16][256];   // 64 KB: per-wave 16-row x-tile
    const int tid = threadIdx.x;
    const int l = tid & 63;
    const int wv = tid >> 6;
    float* xbase = &xs[wv][0][0];

    // B fragments -> VGPRs (32 x 1KB lane-contiguous loads, L2-hot)
    half8 breg[32];
    #pragma unroll
    for (int i = 0; i < 32; ++i) breg[i] = Bf[i * 64 + l];

    // bias per c-tile (scalar-ish loads, uniform)
    float bb[4];
    #pragma unroll
    for (int c = 0; c < 4; ++c) bb[c] = bsum[c * 16 + (l & 15)];

    const int wgid = (blockIdx.x * 256 + tid) >> 6;   // 0..2047
    const int rr = l & 15;
    const int swz = (rr & 7) << 4;

    for (int i = 0; i < 5; ++i) {
        const int tile = wgid * 5 + i;
        const int row0 = tile * 16;

        // issue 16 fully-coalesced row loads (1KB contiguous each)
        #pragma unroll
        for (int r = 0; r < 16; ++r) {
            const int src = (l << 4) ^ ((r & 7) << 4);   // byte offset in row
            gld16(x + (size_t)(row0 + r) * DIN + (src >> 2), xbase + r * 256);
        }
        asm volatile("s_waitcnt vmcnt(0)" ::: "memory");   // tile (and breg) ready
        __builtin_amdgcn_sched_barrier(0);

        f32x4 acc[4];
        #pragma unroll
        for (int c = 0; c < 4; ++c) acc[c] = (f32x4)0.0f;

        const char* rowp = (const char*)(xbase + rr * 256);
        #pragma unroll
        for (int s = 0; s < 8; ++s) {
            const int b0 = s * 128 + ((l >> 4) << 5);
            f32x4 va = *(const f32x4*)(rowp + (b0 ^ swz));
            f32x4 vb = *(const f32x4*)(rowp + ((b0 + 16) ^ swz));
            float fv[8] = {va.x, va.y, va.z, va.w, vb.x, vb.y, vb.z, vb.w};
            half8 ah, al;
            #pragma unroll
            for (int j = 0; j < 8; ++j) {
                _Float16 hi = (_Float16)fv[j];
                ah[j] = hi;
                al[j] = (_Float16)(fv[j] - (float)hi);
            }
            #pragma unroll
            for (int c = 0; c < 4; ++c) {
                acc[c] = __builtin_amdgcn_mfma_f32_16x16x32_f16(ah, breg[c * 8 + s], acc[c], 0, 0, 0);
                acc[c] = __builtin_amdgcn_mfma_f32_16x16x32_f16(al, breg[c * 8 + s], acc[c], 0, 0, 0);
            }
        }

        // epilogue: bias + f16 pack + coalesced fragment-layout store (8B/lane)
        #pragma unroll
        for (int c = 0; c < 4; ++c) {
            half4 hv;
            hv[0] = (_Float16)(acc[c][0] + bb[c]);
            hv[1] = (_Float16)(acc[c][1] + bb[c]);
            hv[2] = (_Float16)(acc[c][2] + bb[c]);
            hv[3] = (_Float16)(acc[c][3] + bb[c]);
            *(half4*)(xgH + (size_t)tile * 1024 + c * 256 + l * 4) = hv;
        }

        // fence: this tile's ds_reads complete before next tile overwrites xs
        asm volatile("s_waitcnt lgkmcnt(0)" ::: "memory");
        __builtin_amdgcn_sched_barrier(0);
    }
}

// K2: fused 2-layer LSTM recurrence + per-block BN partial sums.
// xg read (f16) from fragment layout, all 10 timesteps prefetched up front.
__global__ __launch_bounds__(256) void k_lstm(
        const _Float16* __restrict__ xgH, const float* __restrict__ whh0,
        const float* __restrict__ wih1, const float* __restrict__ whh1,
        const float* __restrict__ bi1, const float* __restrict__ bh1,
        _Float16* __restrict__ flatH, float* __restrict__ psumT,
        float* __restrict__ psqT) {
    __shared__ float ls[4][NF];   // per-wave h1 history for BN partials
    const int g = threadIdx.x & 63;
    const int wv = threadIdx.x >> 6;
    const int b = blockIdx.x * 4 + wv;

    float xv[TT];
    #pragma unroll
    for (int t = 0; t < TT; ++t) {
        const int row = b * TT + t;
        const int addr = ((row >> 4) << 10) + ((g >> 4) << 8) +
                         (((row >> 2) & 3) << 6) + ((g & 15) << 2) + (row & 3);
        xv[t] = (float)xgH[addr];
    }

    float w0[16], w1[16], w2[16];
    #pragma unroll
    for (int q = 0; q < 4; ++q) {
        float4 v0 = *(const float4*)(whh0 + g * HH + q * 4);
        w0[q*4+0] = v0.x; w0[q*4+1] = v0.y; w0[q*4+2] = v0.z; w0[q*4+3] = v0.w;
        float4 v1 = *(const float4*)(wih1 + g * HH + q * 4);
        w1[q*4+0] = v1.x; w1[q*4+1] = v1.y; w1[q*4+2] = v1.z; w1[q*4+3] = v1.w;
        float4 v2 = *(const float4*)(whh1 + g * HH + q * 4);
        w2[q*4+0] = v2.x; w2[q*4+1] = v2.y; w2[q*4+2] = v2.z; w2[q*4+3] = v2.w;
    }
    const float bias1 = bi1[g] + bh1[g];
    const bool isg = (g & 48) == 32;
    const float m1 = isg ? 2.0f : 1.0f;   // unified sig/tanh
    const float b2 = isg ? -1.0f : 0.0f;
    float h0 = 0.0f, c0 = 0.0f, h1 = 0.0f, c1 = 0.0f;

    #pragma unroll
    for (int t = 0; t < TT; ++t) {
        float s0 = xv[t], s1 = 0.0f, s2 = 0.0f, s3 = 0.0f;
        #pragma unroll
        for (int q = 0; q < 4; ++q) {
            s0 += rl_(h0, 4*q + 0) * w0[4*q + 0];
            s1 += rl_(h0, 4*q + 1) * w0[4*q + 1];
            s2 += rl_(h0, 4*q + 2) * w0[4*q + 2];
            s3 += rl_(h0, 4*q + 3) * w0[4*q + 3];
        }
        float z = ((s0 + s1) + (s2 + s3)) * m1;
        float a = m1 / (1.0f + __expf(-z)) + b2;
        float af = __shfl_down(a, 16, 64);
        float ac = __shfl_down(a, 32, 64);
        float ao = __shfl_down(a, 48, 64);
        c0 = af * c0 + a * ac;
        float e0 = __expf(2.0f * c0);
        h0 = ao * (1.0f - 2.0f / (e0 + 1.0f));

        float u0 = bias1, u1 = 0.0f, u2 = 0.0f, u3 = 0.0f;
        float v0 = 0.0f, v1 = 0.0f, v2 = 0.0f, v3 = 0.0f;
        #pragma unroll
        for (int q = 0; q < 4; ++q) {
            u0 += rl_(h0, 4*q + 0) * w1[4*q + 0];
            u1 += rl_(h0, 4*q + 1) * w1[4*q + 1];
            u2 += rl_(h0, 4*q + 2) * w1[4*q + 2];
            u3 += rl_(h0, 4*q + 3) * w1[4*q + 3];
            v0 += rl_(h1, 4*q + 0) * w2[4*q + 0];
            v1 += rl_(h1, 4*q + 1) * w2[4*q + 1];
            v2 += rl_(h1, 4*q + 2) * w2[4*q + 2];
            v3 += rl_(h1, 4*q + 3) * w2[4*q + 3];
        }
        float z1 = (((u0 + v0) + (u1 + v1)) + ((u2 + v2) + (u3 + v3))) * m1;
        float a1 = m1 / (1.0f + __expf(-z1)) + b2;
        af = __shfl_down(a1, 16, 64);
        ac = __shfl_down(a1, 32, 64);
        ao = __shfl_down(a1, 48, 64);
        c1 = af * c1 + a1 * ac;
        float e1 = __expf(2.0f * c1);
        h1 = ao * (1.0f - 2.0f / (e1 + 1.0f));

        if (g < HH) {
            flatH[(size_t)b * NF + t * HH + g] = (_Float16)h1;
            ls[wv][t * HH + g] = h1;
        }
    }

    // BN partials: reduce the block's 4 samples; transposed [f][4096] layout
    // so k_bnB reads coalesced.
    __syncthreads();
    const int tid = threadIdx.x;
    if (tid < NF) {
        float a0 = ls[0][tid], a1 = ls[1][tid], a2 = ls[2][tid], a3 = ls[3][tid];
        psumT[(size_t)tid * 4096 + blockIdx.x] = (a0 + a1) + (a2 + a3);
        psqT[(size_t)tid * 4096 + blockIdx.x] =
            (a0 * a0 + a1 * a1) + (a2 * a2 + a3 * a3);
    }
}

// K3: reduce 4096 block-partials per feature -> fused BN scale/shift.
__global__ __launch_bounds__(256) void k_bnB(
        const float* __restrict__ psumT, const float* __restrict__ psqT,
        const float* __restrict__ gamma, const float* __restrict__ beta,
        float* __restrict__ scale, float* __restrict__ shift) {
    const int f = blockIdx.x;
    const int tid = threadIdx.x;
    const float* ps = psumT + (size_t)f * 4096;
    const float* pq = psqT + (size_t)f * 4096;
    float s = 0.0f, q = 0.0f;
    for (int p = tid; p < 4096; p += 256) { s += ps[p]; q += pq[p]; }
    #pragma unroll
    for (int o = 32; o > 0; o >>= 1) {
        s += __shfl_down(s, o, 64);
        q += __shfl_down(q, o, 64);
    }
    __shared__ float rs[4], rq[4];
    const int wv = tid >> 6;
    if ((tid & 63) == 0) { rs[wv] = s; rq[wv] = q; }
    __syncthreads();
    if (tid == 0) {
        float S = rs[0] + rs[1] + rs[2] + rs[3];
        float Q = rq[0] + rq[1] + rq[2] + rq[3];
        float mean = S * (1.0f / NB);
        float var = Q * (1.0f / NB) - mean * mean;
        float sc = gamma[f] * rsqrtf(var + 1e-5f);
        scale[f] = sc;
        shift[f] = beta[f] - mean * sc;
    }
}

// K4: BN-apply + LeakyReLU + concat + FC(162->2) + softmax (f16 flat).
__global__ __launch_bounds__(256) void k_fc(
        const _Float16* __restrict__ flatH, const float* __restrict__ scale,
        const float* __restrict__ shift, const float* __restrict__ ag,
        const float* __restrict__ fcw, const float* __restrict__ fcb,
        float* __restrict__ out) {
    const int lane = threadIdx.x & 63;
    const int b = blockIdx.x * 4 + (threadIdx.x >> 6);
    const _Float16* fr = flatH + (size_t)b * NF;
    float p0 = 0.0f, p1 = 0.0f;
    #pragma unroll
    for (int i = 0; i < 3; ++i) {
        const int f = lane + i * 64;
        if (f < NF) {
            float xn = (float)fr[f] * scale[f] + shift[f];
            float a = xn >= 0.0f ? xn : 0.01f * xn;
            p0 += a * fcw[f];
            p1 += a * fcw[162 + f];
        }
    }
    #pragma unroll
    for (int o = 32; o > 0; o >>= 1) {
        p0 += __shfl_down(p0, o, 64);
        p1 += __shfl_down(p1, o, 64);
    }
    if (lane == 0) {
        float a0 = ag[(size_t)b * 2 + 0], a1 = ag[(size_t)b * 2 + 1];
        float l0 = p0 + a0 * fcw[160] + a1 * fcw[161] + fcb[0];
        float l1 = p1 + a0 * fcw[162 + 160] + a1 * fcw[162 + 161] + fcb[1];
        float m = fmaxf(l0, l1);
        float e0 = __expf(l0 - m), e1 = __expf(l1 - m);
        float inv = 1.0f / (e0 + e1);
        out[(size_t)b * 2 + 0] = e0 * inv;
        out[(size_t)b * 2 + 1] = e1 * inv;
    }
}

extern "C" void kernel_launch(void* const* d_in, const int* in_sizes, int n_in,
                              void* d_out, int out_size, void* d_ws, size_t ws_size,
                              hipStream_t stream) {
    const float* x     = (const float*)d_in[0];
    const float* ag    = (const float*)d_in[1];
    const float* wih0  = (const float*)d_in[2];
    const float* whh0  = (const float*)d_in[3];
    const float* bih0  = (const float*)d_in[4];
    const float* bhh0  = (const float*)d_in[5];
    const float* wih1  = (const float*)d_in[6];
    const float* whh1  = (const float*)d_in[7];
    const float* bih1  = (const float*)d_in[8];
    const float* bhh1  = (const float*)d_in[9];
    const float* gamma = (const float*)d_in[10];
    const float* beta  = (const float*)d_in[11];
    const float* fcw   = (const float*)d_in[12];
    const float* fcb   = (const float*)d_in[13];
    float* out = (float*)d_out;

    float* ws = (float*)d_ws;
    _Float16* xgH   = (_Float16*)ws;               // 10,485,760 halfs
    _Float16* flatH = (_Float16*)(ws + 5242880);   //  2,621,440 halfs
    float* psumT = ws + 6553600;                   //    655,360 (160 x 4096)
    float* psqT  = ws + 7208960;                   //    655,360
    float* scale = ws + 7864320;                   //        160
    float* shift = ws + 7864480;                   //        160
    half8* Bf    = (half8*)(ws + 7864640);         //      8,192 f32-slots (32 KB)
    float* bsum  = ws + 7872832;                   //         64

    k_prep<<<dim3(8),    dim3(256), 0, stream>>>(wih0, bih0, bhh0, Bf, bsum);
    k_proj<<<dim3(512),  dim3(256), 0, stream>>>(x, Bf, bsum, xgH);
    k_lstm<<<dim3(4096), dim3(256), 0, stream>>>(xgH, whh0, wih1, whh1, bih1, bhh1,
                                                 flatH, psumT, psqT);
    k_bnB<<<dim3(160),  dim3(256), 0, stream>>>(psumT, psqT, gamma, beta, scale, shift);
    k_fc<<<dim3(4096),  dim3(256), 0, stream>>>(flatH, scale, shift, ag, fcw, fcb, out);
}